// Round 3
// baseline (35.475 us; speedup 1.0000x reference)
//
#include <hip/hip_runtime.h>
#include <hip/hip_cooperative_groups.h>

namespace cg = cooperative_groups;

// Reference reduction (proven round 0/1, absmax 0.0):
//   nn_idx[0] == 0 always  =>  exp_neighbor = exp(relu(features[b,0,:]))
//   gamma[i] = max_c( f_ic * exp(f_ic - f_0c) ) / max_c f_ic,  f = relu(features)
//   out      = gamma / ||gamma||_2 per cloud, concatenated.  coords are dead.
//
// Single cooperative dispatch: phase 1 computes gamma (kept in registers) and
// per-block partial sum(gamma^2) -> d_ws; grid.sync(); phase 2 sums the 48
// partials per cloud in fixed order (deterministic) and writes out once,
// normalized. Partials go through agent-scope atomics (per-XCD L2s are not
// cross-coherent; grid.sync orders execution, atomics guarantee visibility).

static constexpr int NPTS = 12288;
static constexpr int CCH  = 32;
static constexpr int BLK  = 256;
static constexpr int NBLK = NPTS / BLK;  // 48 blocks per cloud

__global__ void __launch_bounds__(BLK) fused_kernel(const float* __restrict__ feats,
                                                    float* __restrict__ out,
                                                    float* __restrict__ partials) {
    const int b = blockIdx.y;
    const float* base = feats + (size_t)b * NPTS * CCH;

    // relu(f[0,:]) — wave-uniform address -> scalar loads, L1-resident.
    float f0[CCH];
#pragma unroll
    for (int q = 0; q < CCH / 4; ++q) {
        float4 v = reinterpret_cast<const float4*>(base)[q];
        f0[4 * q + 0] = fmaxf(v.x, 0.0f);
        f0[4 * q + 1] = fmaxf(v.y, 0.0f);
        f0[4 * q + 2] = fmaxf(v.z, 0.0f);
        f0[4 * q + 3] = fmaxf(v.w, 0.0f);
    }

    const int i = blockIdx.x * BLK + threadIdx.x;
    const float4* row = reinterpret_cast<const float4*>(base + (size_t)i * CCH);

    float fm = 0.0f, g = 0.0f;
#pragma unroll
    for (int q = 0; q < CCH / 4; ++q) {
        float4 v = row[q];
        float x0 = fmaxf(v.x, 0.0f), x1 = fmaxf(v.y, 0.0f);
        float x2 = fmaxf(v.z, 0.0f), x3 = fmaxf(v.w, 0.0f);
        fm = fmaxf(fm, fmaxf(fmaxf(x0, x1), fmaxf(x2, x3)));
        g = fmaxf(g, x0 * __expf(x0 - f0[4 * q + 0]));
        g = fmaxf(g, x1 * __expf(x1 - f0[4 * q + 1]));
        g = fmaxf(g, x2 * __expf(x2 - f0[4 * q + 2]));
        g = fmaxf(g, x3 * __expf(x3 - f0[4 * q + 3]));
    }
    const float gamma = g / fm;  // stays in a register across the grid sync

    // Deterministic block reduction of gamma^2 (fixed shuffle + LDS order).
    float s = gamma * gamma;
#pragma unroll
    for (int off = 32; off > 0; off >>= 1) s += __shfl_down(s, off);
    __shared__ float red[BLK / 64];
    const int lane = threadIdx.x & 63;
    const int wv   = threadIdx.x >> 6;
    if (lane == 0) red[wv] = s;
    __syncthreads();
    if (threadIdx.x == 0) {
        float p = (red[0] + red[1]) + (red[2] + red[3]);
        __hip_atomic_store(&partials[b * NBLK + blockIdx.x], p,
                           __ATOMIC_RELAXED, __HIP_MEMORY_SCOPE_AGENT);
    }

    cg::this_grid().sync();

    // Fixed-order sum of the 48 partials: deterministic across all blocks.
    float t = 0.0f;
#pragma unroll
    for (int j = 0; j < NBLK; ++j)
        t += __hip_atomic_load(&partials[b * NBLK + j],
                               __ATOMIC_RELAXED, __HIP_MEMORY_SCOPE_AGENT);

    out[(size_t)b * NPTS + i] = gamma * rsqrtf(t);
}

extern "C" void kernel_launch(void* const* d_in, const int* in_sizes, int n_in,
                              void* d_out, int out_size, void* d_ws, size_t ws_size,
                              hipStream_t stream) {
    const float* feats = (const float*)d_in[1];  // features [B,N,C] f32; coords dead
    float* out = (float*)d_out;                  // [B*N] f32
    float* partials = (float*)d_ws;              // [B,48] f32, fully rewritten every call

    const int B = out_size / NPTS;
    dim3 grid(NBLK, B), block(BLK);
    void* args[] = {(void*)&feats, (void*)&out, (void*)&partials};
    hipLaunchCooperativeKernel(reinterpret_cast<void*>(fused_kernel),
                               grid, block, args, 0, stream);
}